// Round 1
// baseline (448.833 us; speedup 1.0000x reference)
//
#include <hip/hip_runtime.h>
#include <stdint.h>

#define NB 4
#define CCH 256
#define HW 4096
#define HEADS 4
#define DH 64
#define SLEN 4096
#define EPSV 1e-5f
#define NEG_INF (-__builtin_inff())

typedef unsigned short u16;
typedef __bf16 bf16x8 __attribute__((ext_vector_type(8)));
typedef float f32x4 __attribute__((ext_vector_type(4)));

__device__ __forceinline__ u16 f2bf(float f) {
  union { float f; uint32_t u; } v; v.f = f;
  uint32_t r = v.u + 0x7FFFu + ((v.u >> 16) & 1u);
  return (u16)(r >> 16);
}

// ---------------- BN stats: one block per channel ----------------
__global__ __launch_bounds__(256) void k_bnstats(
    const float* __restrict__ x, const float* __restrict__ gamma,
    const float* __restrict__ beta, float* __restrict__ ab) {
  int ch = blockIdx.x, t = threadIdx.x;
  float s = 0.f, ss = 0.f;
  for (int n = 0; n < NB; ++n) {
    const float4* p = (const float4*)(x + ((size_t)(n * CCH + ch)) * HW);
    for (int i = t; i < HW / 4; i += 256) {
      float4 v = p[i];
      s += v.x + v.y + v.z + v.w;
      ss += v.x * v.x + v.y * v.y + v.z * v.z + v.w * v.w;
    }
  }
#pragma unroll
  for (int m = 32; m >= 1; m >>= 1) {
    s += __shfl_down(s, m);
    ss += __shfl_down(ss, m);
  }
  __shared__ float ls[4], lss[4];
  if ((t & 63) == 0) { ls[t >> 6] = s; lss[t >> 6] = ss; }
  __syncthreads();
  if (t == 0) {
    float S = 0.f, SS = 0.f;
    for (int i = 0; i < 4; ++i) { S += ls[i]; SS += lss[i]; }
    float inv = 1.0f / (float)(NB * HW);
    float mean = S * inv;
    float var = SS * inv - mean * mean;
    float a = gamma[ch] * rsqrtf(var + EPSV);
    ab[ch] = a;
    ab[CCH + ch] = beta[ch] - mean * a;
  }
}

// ---------------- normalize + transpose -> seq bf16 (n, hw, c) ----------------
__global__ __launch_bounds__(256) void k_seq(
    const float* __restrict__ x, const float* __restrict__ ab,
    u16* __restrict__ seq) {
  __shared__ float tile[64][65];
  int pb = blockIdx.x * 64, cb = blockIdx.y * 64, n = blockIdx.z;
  int t = threadIdx.x;
  {
    int cl = t >> 2, pc = (t & 3) * 16;
    float a = ab[cb + cl], b = ab[CCH + cb + cl];
    const float* src = x + ((size_t)(n * CCH + cb + cl)) * HW + pb + pc;
#pragma unroll
    for (int i = 0; i < 4; ++i) {
      float4 v = *(const float4*)(src + i * 4);
      tile[cl][pc + i * 4 + 0] = v.x * a + b;
      tile[cl][pc + i * 4 + 1] = v.y * a + b;
      tile[cl][pc + i * 4 + 2] = v.z * a + b;
      tile[cl][pc + i * 4 + 3] = v.w * a + b;
    }
  }
  __syncthreads();
  {
    int pl = t >> 2, cs = (t & 3) * 16;
    union { u16 u[16]; uint4 v[2]; } tmp;
#pragma unroll
    for (int i = 0; i < 16; ++i) tmp.u[i] = f2bf(tile[cs + i][pl]);
    u16* dst = seq + ((size_t)(n * HW + pb + pl)) * CCH + cb + cs;
    *(uint4*)dst = tmp.v[0];
    *(uint4*)(dst + 8) = tmp.v[1];
  }
}

// ---------------- weights f32 -> bf16 ----------------
__global__ __launch_bounds__(256) void k_cvt(
    const float* __restrict__ qw, const float* __restrict__ pw,
    u16* __restrict__ qwb, u16* __restrict__ pwb) {
  int i = (blockIdx.x * 256 + threadIdx.x) * 4;
  const int NQ = CCH * 3 * CCH;  // 196608
  union { u16 u[4]; uint2 v2; } o;
  if (i < NQ) {
    float4 v = *(const float4*)(qw + i);
    o.u[0] = f2bf(v.x); o.u[1] = f2bf(v.y); o.u[2] = f2bf(v.z); o.u[3] = f2bf(v.w);
    *(uint2*)(qwb + i) = o.v2;
  } else {
    int j = i - NQ;  // < 65536
    float4 v = *(const float4*)(pw + j);
    o.u[0] = f2bf(v.x); o.u[1] = f2bf(v.y); o.u[2] = f2bf(v.z); o.u[3] = f2bf(v.w);
    *(uint2*)(pwb + j) = o.v2;
  }
}

// ---------------- QKV GEMM: seq(16384x256) @ qkv_w(256x768) -> scatter Q/K/V ----------------
__global__ __launch_bounds__(256) void k_qkv(
    const u16* __restrict__ seq, const u16* __restrict__ w,
    u16* __restrict__ Q, u16* __restrict__ K, u16* __restrict__ V) {
  __shared__ __attribute__((aligned(16))) u16 As[64 * 32];
  __shared__ __attribute__((aligned(16))) u16 Bs[64 * 32];
  int Rb = blockIdx.x * 64, Cb = blockIdx.y * 64;
  int t = threadIdx.x, lane = t & 63, wv = t >> 6;
  int wr = (wv >> 1) * 32, wc = (wv & 1) * 32;
  f32x4 acc[2][2] = {};
  for (int kb = 0; kb < CCH; kb += 32) {
    {
      int r = t >> 2, kc = t & 3;
      uint4 v = *(const uint4*)(seq + ((size_t)(Rb + r)) * CCH + kb + kc * 8);
      *(uint4*)((char*)As + r * 64 + ((kc * 16) ^ ((r & 3) << 4))) = v;
    }
    {
      int k = t >> 3, jc = (t & 7) * 8;
      union { u16 u[8]; uint4 v; } tmp;
      tmp.v = *(const uint4*)(w + ((size_t)(kb + k)) * 768 + Cb + jc);
#pragma unroll
      for (int i2 = 0; i2 < 8; ++i2) {
        int j = jc + i2;
        *(u16*)((char*)Bs + j * 64 + ((k * 2) ^ ((j & 3) << 4))) = tmp.u[i2];
      }
    }
    __syncthreads();
    bf16x8 af[2], bfr[2];
#pragma unroll
    for (int f = 0; f < 2; ++f) {
      int row = wr + f * 16 + (lane & 15);
      af[f] = *(const bf16x8*)((const char*)As + row * 64 +
                               (((lane >> 4) * 16) ^ ((row & 3) << 4)));
      int col = wc + f * 16 + (lane & 15);
      bfr[f] = *(const bf16x8*)((const char*)Bs + col * 64 +
                                (((lane >> 4) * 16) ^ ((col & 3) << 4)));
    }
#pragma unroll
    for (int i2 = 0; i2 < 2; ++i2)
#pragma unroll
      for (int j2 = 0; j2 < 2; ++j2)
        acc[i2][j2] = __builtin_amdgcn_mfma_f32_16x16x32_bf16(af[i2], bfr[j2], acc[i2][j2], 0, 0, 0);
    __syncthreads();
  }
#pragma unroll
  for (int i2 = 0; i2 < 2; ++i2)
#pragma unroll
    for (int j2 = 0; j2 < 2; ++j2)
#pragma unroll
      for (int e = 0; e < 4; ++e) {
        int R = Rb + wr + i2 * 16 + (lane >> 4) * 4 + e;
        int cg = Cb + wc + j2 * 16 + (lane & 15);
        int p = R & (HW - 1);
        int head = p >> 10, m = p & 1023;
        int qn = m * 4 + cg / 192, tt = cg % 192;
        size_t base = (((size_t)((R >> 12) * HEADS + head)) * SLEN + qn) * DH;
        u16 val = f2bf(acc[i2][j2][e]);
        if (tt < 64) Q[base + tt];
        if (tt < 64) Q[base + tt] = val;
        else if (tt < 128) K[base + tt - 64] = val;
        else V[base + tt - 128] = val;
      }
}

// ---------------- flash attention ----------------
__global__ __launch_bounds__(256) void k_attn(
    const u16* __restrict__ Q, const u16* __restrict__ K,
    const u16* __restrict__ V, u16* __restrict__ O) {
  __shared__ __attribute__((aligned(16))) u16 Ks[64 * 64];
  __shared__ __attribute__((aligned(16))) u16 Vts[64 * 64];
  __shared__ __attribute__((aligned(16))) u16 Ps[4][16 * 64];
  int q0 = blockIdx.x * 64, nh = blockIdx.y;
  int t = threadIdx.x, lane = t & 63, wv = t >> 6;
  size_t base = (size_t)nh * SLEN * DH;
  bf16x8 qf[2];
  {
    int q = q0 + wv * 16 + (lane & 15);
    const u16* src = Q + base + (size_t)q * DH + (lane >> 4) * 8;
    qf[0] = *(const bf16x8*)src;
    qf[1] = *(const bf16x8*)(src + 32);
  }
  f32x4 o[4] = {};
  float mrow[4] = {NEG_INF, NEG_INF, NEG_INF, NEG_INF};
  float lrow[4] = {0.f, 0.f, 0.f, 0.f};
  for (int kv0 = 0; kv0 < SLEN; kv0 += 64) {
#pragma unroll
    for (int c = 0; c < 2; ++c) {
      int idx = t + c * 256;
      int r = idx >> 3, dc = idx & 7;
      size_t goff = base + (size_t)(kv0 + r) * DH + dc * 8;
      uint4 kvec = *(const uint4*)(K + goff);
      *(uint4*)((char*)Ks + r * 128 + ((dc * 16) ^ ((r & 7) << 4))) = kvec;
      union { u16 u[8]; uint4 v; } tv;
      tv.v = *(const uint4*)(V + goff);
#pragma unroll
      for (int i2 = 0; i2 < 8; ++i2) {
        int d = dc * 8 + i2;
        *(u16*)((char*)Vts + d * 128 + ((r * 2) ^ ((d & 7) << 4))) = tv.u[i2];
      }
    }
    __syncthreads();
    f32x4 sc[4];
#pragma unroll
    for (int cf = 0; cf < 4; ++cf) {
      f32x4 a = {};
#pragma unroll
      for (int ks = 0; ks < 2; ++ks) {
        int kvr = cf * 16 + (lane & 15);
        bf16x8 b = *(const bf16x8*)((const char*)Ks + kvr * 128 +
                                    ((ks * 64 + (lane >> 4) * 16) ^ ((kvr & 7) << 4)));
        a = __builtin_amdgcn_mfma_f32_16x16x32_bf16(qf[ks], b, a, 0, 0, 0);
      }
      sc[cf] = a;
    }
    float psum[4];
#pragma unroll
    for (int e = 0; e < 4; ++e) {
      float mx = fmaxf(fmaxf(sc[0][e], sc[1][e]), fmaxf(sc[2][e], sc[3][e]));
      mx = fmaxf(mx, __shfl_xor(mx, 1));
      mx = fmaxf(mx, __shfl_xor(mx, 2));
      mx = fmaxf(mx, __shfl_xor(mx, 4));
      mx = fmaxf(mx, __shfl_xor(mx, 8));
      float mn = fmaxf(mrow[e], mx * 0.125f);
      float al = __expf(mrow[e] - mn);
      mrow[e] = mn;
      lrow[e] *= al;
      o[0][e] *= al; o[1][e] *= al; o[2][e] *= al; o[3][e] *= al;
      psum[e] = 0.f;
    }
#pragma unroll
    for (int cf = 0; cf < 4; ++cf) {
#pragma unroll
      for (int e = 0; e < 4; ++e) {
        float p = __expf(sc[cf][e] * 0.125f - mrow[e]);
        psum[e] += p;
        int row = (lane >> 4) * 4 + e;
        int col = cf * 16 + (lane & 15);
        *(u16*)((char*)Ps[wv] + row * 128 + ((col * 2) ^ ((row & 7) << 4))) = f2bf(p);
      }
    }
#pragma unroll
    for (int e = 0; e < 4; ++e) {
      float ps = psum[e];
      ps += __shfl_xor(ps, 1);
      ps += __shfl_xor(ps, 2);
      ps += __shfl_xor(ps, 4);
      ps += __shfl_xor(ps, 8);
      lrow[e] += ps;
    }
#pragma unroll
    for (int df = 0; df < 4; ++df) {
#pragma unroll
      for (int ks = 0; ks < 2; ++ks) {
        int pr = lane & 15;
        bf16x8 a = *(const bf16x8*)((const char*)Ps[wv] + pr * 128 +
                                    ((ks * 64 + (lane >> 4) * 16) ^ ((pr & 7) << 4)));
        int dr = df * 16 + (lane & 15);
        bf16x8 b = *(const bf16x8*)((const char*)Vts + dr * 128 +
                                    ((ks * 64 + (lane >> 4) * 16) ^ ((dr & 7) << 4)));
        o[df] = __builtin_amdgcn_mfma_f32_16x16x32_bf16(a, b, o[df], 0, 0, 0);
      }
    }
    __syncthreads();
  }
  int n = nh >> 2, head = nh & 3;
#pragma unroll
  for (int df = 0; df < 4; ++df)
#pragma unroll
    for (int e = 0; e < 4; ++e) {
      int qn = q0 + wv * 16 + (lane >> 4) * 4 + e;
      int d = df * 16 + (lane & 15);
      float val = o[df][e] / lrow[e];
      size_t off = (((size_t)n * HW) + head * 1024 + (qn >> 2)) * CCH + (qn & 3) * DH + d;
      O[off] = f2bf(val);
    }
}

// ---------------- proj GEMM + bias + transpose to (n, c, hw) fp32 ----------------
__global__ __launch_bounds__(256) void k_proj(
    const u16* __restrict__ A, const u16* __restrict__ W,
    const float* __restrict__ bias, float* __restrict__ out) {
  __shared__ __attribute__((aligned(16))) u16 As[64 * 32];
  __shared__ __attribute__((aligned(16))) u16 Bs[64 * 32];
  int Rb = blockIdx.x * 64, Cb = blockIdx.y * 64;
  int t = threadIdx.x, lane = t & 63, wv = t >> 6;
  int wr = (wv >> 1) * 32, wc = (wv & 1) * 32;
  f32x4 acc[2][2] = {};
  for (int kb = 0; kb < CCH; kb += 32) {
    {
      int r = t >> 2, kc = t & 3;
      uint4 v = *(const uint4*)(A + ((size_t)(Rb + r)) * CCH + kb + kc * 8);
      *(uint4*)((char*)As + r * 64 + ((kc * 16) ^ ((r & 3) << 4))) = v;
    }
    {
      int k = t >> 3, jc = (t & 7) * 8;
      union { u16 u[8]; uint4 v; } tmp;
      tmp.v = *(const uint4*)(W + ((size_t)(kb + k)) * CCH + Cb + jc);
#pragma unroll
      for (int i2 = 0; i2 < 8; ++i2) {
        int j = jc + i2;
        *(u16*)((char*)Bs + j * 64 + ((k * 2) ^ ((j & 3) << 4))) = tmp.u[i2];
      }
    }
    __syncthreads();
    bf16x8 af[2], bfr[2];
#pragma unroll
    for (int f = 0; f < 2; ++f) {
      int row = wr + f * 16 + (lane & 15);
      af[f] = *(const bf16x8*)((const char*)As + row * 64 +
                               (((lane >> 4) * 16) ^ ((row & 3) << 4)));
      int col = wc + f * 16 + (lane & 15);
      bfr[f] = *(const bf16x8*)((const char*)Bs + col * 64 +
                                (((lane >> 4) * 16) ^ ((col & 3) << 4)));
    }
#pragma unroll
    for (int i2 = 0; i2 < 2; ++i2)
#pragma unroll
      for (int j2 = 0; j2 < 2; ++j2)
        acc[i2][j2] = __builtin_amdgcn_mfma_f32_16x16x32_bf16(af[i2], bfr[j2], acc[i2][j2], 0, 0, 0);
    __syncthreads();
  }
#pragma unroll
  for (int i2 = 0; i2 < 2; ++i2)
#pragma unroll
    for (int j2 = 0; j2 < 2; ++j2)
#pragma unroll
      for (int e = 0; e < 4; ++e) {
        int R = Rb + wr + i2 * 16 + (lane >> 4) * 4 + e;
        int cg = Cb + wc + j2 * 16 + (lane & 15);
        out[((size_t)((R >> 12) * CCH + cg)) * HW + (R & (HW - 1))] =
            acc[i2][j2][e] + bias[cg];
      }
}

extern "C" void kernel_launch(void* const* d_in, const int* in_sizes, int n_in,
                              void* d_out, int out_size, void* d_ws, size_t ws_size,
                              hipStream_t stream) {
  (void)in_sizes; (void)n_in; (void)out_size; (void)ws_size;
  const float* x      = (const float*)d_in[0];
  const float* gamma  = (const float*)d_in[1];
  const float* beta   = (const float*)d_in[2];
  const float* qkv_w  = (const float*)d_in[3];
  const float* proj_w = (const float*)d_in[4];
  const float* proj_b = (const float*)d_in[5];

  char* ws = (char*)d_ws;
  size_t off = 0;
  float* ab = (float*)(ws + off); off += 4096;
  u16* seq  = (u16*)(ws + off);  off += (size_t)NB * HW * CCH * 2;       // 8 MB
  u16* qwb  = (u16*)(ws + off);  off += (size_t)CCH * 3 * CCH * 2;      // 384 KB
  u16* pwb  = (u16*)(ws + off);  off += (size_t)CCH * CCH * 2;          // 128 KB
  u16* Qb   = (u16*)(ws + off);  off += (size_t)NB * HEADS * SLEN * DH * 2;  // 8 MB
  u16* Kb   = (u16*)(ws + off);  off += (size_t)NB * HEADS * SLEN * DH * 2;
  u16* Vb   = (u16*)(ws + off);  off += (size_t)NB * HEADS * SLEN * DH * 2;
  u16* oseq = (u16*)(ws + off);  off += (size_t)NB * HW * CCH * 2;

  k_bnstats<<<256, 256, 0, stream>>>(x, gamma, beta, ab);
  k_seq<<<dim3(HW / 64, CCH / 64, NB), 256, 0, stream>>>(x, ab, seq);
  k_cvt<<<256, 256, 0, stream>>>(qkv_w, proj_w, qwb, pwb);
  k_qkv<<<dim3((NB * HW) / 64, 768 / 64), 256, 0, stream>>>(seq, qwb, Qb, Kb, Vb);
  k_attn<<<dim3(SLEN / 64, NB * HEADS), 256, 0, stream>>>(Qb, Kb, Vb, oseq);
  k_proj<<<dim3((NB * HW) / 64, CCH / 64), 256, 0, stream>>>(oseq, pwb, proj_b, (float*)d_out);
}

// Round 2
// 298.438 us; speedup vs baseline: 1.5039x; 1.5039x over previous
//
#include <hip/hip_runtime.h>
#include <stdint.h>

#define NB 4
#define CCH 256
#define HW 4096
#define HEADS 4
#define DH 64
#define SLEN 4096
#define EPSV 1e-5f
#define NEG_INF (-__builtin_inff())
#define QSCALE (0.125f * 1.44269504088896340736f)

typedef unsigned short u16;
typedef __bf16 bf16x8 __attribute__((ext_vector_type(8)));
typedef float f32x4 __attribute__((ext_vector_type(4)));

__device__ __forceinline__ u16 f2bf(float f) {
  union { float f; uint32_t u; } v; v.f = f;
  uint32_t r = v.u + 0x7FFFu + ((v.u >> 16) & 1u);
  return (u16)(r >> 16);
}

// ---------------- BN stats: one block per channel ----------------
__global__ __launch_bounds__(256) void k_bnstats(
    const float* __restrict__ x, const float* __restrict__ gamma,
    const float* __restrict__ beta, float* __restrict__ ab) {
  int ch = blockIdx.x, t = threadIdx.x;
  float s = 0.f, ss = 0.f;
  for (int n = 0; n < NB; ++n) {
    const float4* p = (const float4*)(x + ((size_t)(n * CCH + ch)) * HW);
    for (int i = t; i < HW / 4; i += 256) {
      float4 v = p[i];
      s += v.x + v.y + v.z + v.w;
      ss += v.x * v.x + v.y * v.y + v.z * v.z + v.w * v.w;
    }
  }
#pragma unroll
  for (int m = 32; m >= 1; m >>= 1) {
    s += __shfl_down(s, m);
    ss += __shfl_down(ss, m);
  }
  __shared__ float ls[4], lss[4];
  if ((t & 63) == 0) { ls[t >> 6] = s; lss[t >> 6] = ss; }
  __syncthreads();
  if (t == 0) {
    float S = 0.f, SS = 0.f;
    for (int i = 0; i < 4; ++i) { S += ls[i]; SS += lss[i]; }
    float inv = 1.0f / (float)(NB * HW);
    float mean = S * inv;
    float var = SS * inv - mean * mean;
    float a = gamma[ch] * rsqrtf(var + EPSV);
    ab[ch] = a;
    ab[CCH + ch] = beta[ch] - mean * a;
  }
}

// ---------------- normalize + transpose -> seq bf16 (n, hw, c) ----------------
__global__ __launch_bounds__(256) void k_seq(
    const float* __restrict__ x, const float* __restrict__ ab,
    u16* __restrict__ seq) {
  __shared__ float tile[64][65];
  int pb = blockIdx.x * 64, cb = blockIdx.y * 64, n = blockIdx.z;
  int t = threadIdx.x;
  {
    int cl = t >> 2, pc = (t & 3) * 16;
    float a = ab[cb + cl], b = ab[CCH + cb + cl];
    const float* src = x + ((size_t)(n * CCH + cb + cl)) * HW + pb + pc;
#pragma unroll
    for (int i = 0; i < 4; ++i) {
      float4 v = *(const float4*)(src + i * 4);
      tile[cl][pc + i * 4 + 0] = v.x * a + b;
      tile[cl][pc + i * 4 + 1] = v.y * a + b;
      tile[cl][pc + i * 4 + 2] = v.z * a + b;
      tile[cl][pc + i * 4 + 3] = v.w * a + b;
    }
  }
  __syncthreads();
  {
    int pl = t >> 2, cs = (t & 3) * 16;
    union { u16 u[16]; uint4 v[2]; } tmp;
#pragma unroll
    for (int i = 0; i < 16; ++i) tmp.u[i] = f2bf(tile[cs + i][pl]);
    u16* dst = seq + ((size_t)(n * HW + pb + pl)) * CCH + cb + cs;
    *(uint4*)dst = tmp.v[0];
    *(uint4*)(dst + 8) = tmp.v[1];
  }
}

// ---------------- weights f32 -> bf16 ----------------
__global__ __launch_bounds__(256) void k_cvt(
    const float* __restrict__ qw, const float* __restrict__ pw,
    u16* __restrict__ qwb, u16* __restrict__ pwb) {
  int i = (blockIdx.x * 256 + threadIdx.x) * 4;
  const int NQ = CCH * 3 * CCH;  // 196608
  union { u16 u[4]; uint2 v2; } o;
  if (i < NQ) {
    float4 v = *(const float4*)(qw + i);
    o.u[0] = f2bf(v.x); o.u[1] = f2bf(v.y); o.u[2] = f2bf(v.z); o.u[3] = f2bf(v.w);
    *(uint2*)(qwb + i) = o.v2;
  } else {
    int j = i - NQ;  // < 65536
    float4 v = *(const float4*)(pw + j);
    o.u[0] = f2bf(v.x); o.u[1] = f2bf(v.y); o.u[2] = f2bf(v.z); o.u[3] = f2bf(v.w);
    *(uint2*)(pwb + j) = o.v2;
  }
}

// ---------------- QKV GEMM: seq(16384x256) @ qkv_w(256x768) -> scatter Q/K/Vt ----
// Q gets the softmax scale (0.125 * log2e) folded in; V is written TRANSPOSED
// as Vt[nh][d][kv] so attention can read V^T fragments directly from global.
__global__ __launch_bounds__(256) void k_qkv(
    const u16* __restrict__ seq, const u16* __restrict__ w,
    u16* __restrict__ Q, u16* __restrict__ K, u16* __restrict__ Vt) {
  __shared__ __attribute__((aligned(16))) u16 As[64 * 32];
  __shared__ __attribute__((aligned(16))) u16 Bs[64 * 32];
  int Rb = blockIdx.x * 64, Cb = blockIdx.y * 64;
  int t = threadIdx.x, lane = t & 63, wv = t >> 6;
  int wr = (wv >> 1) * 32, wc = (wv & 1) * 32;
  f32x4 acc[2][2] = {};
  for (int kb = 0; kb < CCH; kb += 32) {
    {
      int r = t >> 2, kc = t & 3;
      uint4 v = *(const uint4*)(seq + ((size_t)(Rb + r)) * CCH + kb + kc * 8);
      *(uint4*)((char*)As + r * 64 + ((kc * 16) ^ ((r & 3) << 4))) = v;
    }
    {
      int k = t >> 3, jc = (t & 7) * 8;
      union { u16 u[8]; uint4 v; } tmp;
      tmp.v = *(const uint4*)(w + ((size_t)(kb + k)) * 768 + Cb + jc);
#pragma unroll
      for (int i2 = 0; i2 < 8; ++i2) {
        int j = jc + i2;
        *(u16*)((char*)Bs + j * 64 + ((k * 2) ^ ((j & 3) << 4))) = tmp.u[i2];
      }
    }
    __syncthreads();
    bf16x8 af[2], bfr[2];
#pragma unroll
    for (int f = 0; f < 2; ++f) {
      int row = wr + f * 16 + (lane & 15);
      af[f] = *(const bf16x8*)((const char*)As + row * 64 +
                               (((lane >> 4) * 16) ^ ((row & 3) << 4)));
      int col = wc + f * 16 + (lane & 15);
      bfr[f] = *(const bf16x8*)((const char*)Bs + col * 64 +
                                (((lane >> 4) * 16) ^ ((col & 3) << 4)));
    }
#pragma unroll
    for (int i2 = 0; i2 < 2; ++i2)
#pragma unroll
      for (int j2 = 0; j2 < 2; ++j2)
        acc[i2][j2] = __builtin_amdgcn_mfma_f32_16x16x32_bf16(af[i2], bfr[j2], acc[i2][j2], 0, 0, 0);
    __syncthreads();
  }
#pragma unroll
  for (int i2 = 0; i2 < 2; ++i2)
#pragma unroll
    for (int j2 = 0; j2 < 2; ++j2)
#pragma unroll
      for (int e = 0; e < 4; ++e) {
        int R = Rb + wr + i2 * 16 + (lane >> 4) * 4 + e;
        int cg = Cb + wc + j2 * 16 + (lane & 15);
        int p = R & (HW - 1);
        int head = p >> 10, mq = p & 1023;
        int qn = mq * 4 + cg / 192, tt = cg % 192;
        int nhx = (R >> 12) * HEADS + head;
        float a = acc[i2][j2][e];
        if (tt < 64)
          Q[((size_t)nhx * SLEN + qn) * DH + tt] = f2bf(a * QSCALE);
        else if (tt < 128)
          K[((size_t)nhx * SLEN + qn) * DH + tt - 64] = f2bf(a);
        else
          Vt[(size_t)nhx * SLEN * DH + (size_t)(tt - 128) * SLEN + qn] = f2bf(a);
      }
}

// ---------------- flash attention: swapped QK^T, no K/V LDS staging ----------------
// Block = 2 waves, same 64 q rows, kv-split in half per wave, merge at end.
// Per-wave LDS only for the P round-trip (XOR-swizzled, vectorized) -> no
// __syncthreads in the main loop at all.
__global__ __launch_bounds__(128, 2) void k_attn(
    const u16* __restrict__ Q, const u16* __restrict__ K,
    const u16* __restrict__ Vt, u16* __restrict__ O) {
  __shared__ __attribute__((aligned(16))) char smem[16384 + 1024];
  int q0 = blockIdx.x * 64, nh = blockIdx.y;
  int t = threadIdx.x;
  int lane = t & 63, w = t >> 6;
  int l15 = lane & 15, g = lane >> 4;
  size_t base = (size_t)nh * SLEN * DH;
  char* Ps = smem + w * 8192;          // [64 q][64 kv] bf16, 128B rows, swizzled
  int swz = (l15 & 7) << 4;

  // Q fragments (B-operand: col = q = l15, k = d = 32*ks + 8*g + i)
  bf16x8 qv[4][2];
#pragma unroll
  for (int qf = 0; qf < 4; ++qf) {
    const u16* qp = Q + base + (size_t)(q0 + qf * 16 + l15) * DH + g * 8;
    qv[qf][0] = *(const bf16x8*)qp;
    qv[qf][1] = *(const bf16x8*)(qp + 32);
  }

  f32x4 o[4][4] = {};
  float m[4] = {NEG_INF, NEG_INF, NEG_INF, NEG_INF};
  float lsum[4] = {0.f, 0.f, 0.f, 0.f};

  const u16* Kbase = K + base + (size_t)l15 * DH + g * 8;
  const u16* Vbase = Vt + base + (size_t)l15 * SLEN + g * 8;

  const int TILES = SLEN / 64 / 2;  // 32 per wave
  for (int tt = 0; tt < TILES; ++tt) {
    int kv0 = (w * TILES + tt) * 64;
    // K fragments (A-operand: row = kv = cf*16 + l15, k = d)
    bf16x8 kf[4][2];
#pragma unroll
    for (int cf = 0; cf < 4; ++cf) {
      const u16* kp = Kbase + (size_t)(kv0 + cf * 16) * DH;
      kf[cf][0] = *(const bf16x8*)kp;
      kf[cf][1] = *(const bf16x8*)(kp + 32);
    }
    // V^T fragments (B-operand for PV: col = d = df*16 + l15, k = kv)
    bf16x8 vf[4][2];
#pragma unroll
    for (int df = 0; df < 4; ++df) {
      const u16* vp = Vbase + (size_t)(df * 16) * SLEN + kv0;
      vf[df][0] = *(const bf16x8*)vp;
      vf[df][1] = *(const bf16x8*)(vp + 32);
    }
#pragma unroll
    for (int qf = 0; qf < 4; ++qf) {
      // S^T fragment: lane holds kv = cf*16 + 4g + e for q = q0 + qf*16 + l15
      f32x4 st[4];
#pragma unroll
      for (int cf = 0; cf < 4; ++cf) {
        f32x4 a = {};
        a = __builtin_amdgcn_mfma_f32_16x16x32_bf16(kf[cf][0], qv[qf][0], a, 0, 0, 0);
        a = __builtin_amdgcn_mfma_f32_16x16x32_bf16(kf[cf][1], qv[qf][1], a, 0, 0, 0);
        st[cf] = a;
      }
      // in-lane max over 16, then across the 4 g-groups
      float mx = st[0][0];
#pragma unroll
      for (int cf = 0; cf < 4; ++cf)
#pragma unroll
        for (int e = 0; e < 4; ++e) mx = fmaxf(mx, st[cf][e]);
      mx = fmaxf(mx, __shfl_xor(mx, 16));
      mx = fmaxf(mx, __shfl_xor(mx, 32));
      float mn = fmaxf(m[qf], mx);
      float al = exp2f(m[qf] - mn);
      m[qf] = mn;
      lsum[qf] *= al;
      // rescale O rows (rows are q = qf*16 + 4g + e; al lives at lane l15==q)
#pragma unroll
      for (int e = 0; e < 4; ++e) {
        float ae = __shfl(al, (lane & 48) | (((lane >> 4) << 2) + e));
#pragma unroll
        for (int df = 0; df < 4; ++df) o[qf][df][e] *= ae;
      }
      // P = exp2(S - m), pack 4 bf16, one ds_write_b64 per cf
      float ls = 0.f;
#pragma unroll
      for (int cf = 0; cf < 4; ++cf) {
        union { __bf16 h[4]; uint2 v; } pk;
#pragma unroll
        for (int e = 0; e < 4; ++e) {
          float p = exp2f(st[cf][e] - mn);
          ls += p;
          pk.h[e] = (__bf16)p;
        }
        *(uint2*)(Ps + (qf * 16 + l15) * 128 + ((cf * 32 + g * 8) ^ swz)) = pk.v;
      }
      lsum[qf] += ls;
    }
    // PV: A = P (from per-wave LDS), B = V^T fragments
#pragma unroll
    for (int qf = 0; qf < 4; ++qf) {
#pragma unroll
      for (int ks = 0; ks < 2; ++ks) {
        bf16x8 pa = *(const bf16x8*)(Ps + (qf * 16 + l15) * 128 + ((ks * 64 + g * 16) ^ swz));
#pragma unroll
        for (int df = 0; df < 4; ++df)
          o[qf][df] = __builtin_amdgcn_mfma_f32_16x16x32_bf16(pa, vf[df][ks], o[qf][df], 0, 0, 0);
      }
    }
  }
  // reduce l across g-groups (m is already row-global)
#pragma unroll
  for (int qf = 0; qf < 4; ++qf) {
    lsum[qf] += __shfl_xor(lsum[qf], 16);
    lsum[qf] += __shfl_xor(lsum[qf], 32);
  }
  __syncthreads();  // everyone done with Ps
  float* Om = (float*)smem;             // [64 d][64 q] f32, swizzled
  float* mlb = (float*)(smem + 16384);  // [w][qf][m|l][16]
  if (w == 1) {
#pragma unroll
    for (int qf = 0; qf < 4; ++qf)
#pragma unroll
      for (int df = 0; df < 4; ++df) {
        int d = df * 16 + l15;
        int ba = d * 256 + qf * 64 + g * 16;
        *(f32x4*)((char*)smem + (ba ^ ((d & 7) << 4))) = o[qf][df];
      }
  }
  if (lane < 16) {
#pragma unroll
    for (int qf = 0; qf < 4; ++qf) {
      mlb[((w * 4 + qf) * 2 + 0) * 16 + l15] = m[qf];
      mlb[((w * 4 + qf) * 2 + 1) * 16 + l15] = lsum[qf];
    }
  }
  __syncthreads();
  if (w == 0) {
    int n = nh >> 2, head = nh & 3;
#pragma unroll
    for (int qf = 0; qf < 4; ++qf) {
      f32x4 m0 = *(f32x4*)&mlb[((0 + qf) * 2 + 0) * 16 + g * 4];
      f32x4 l0 = *(f32x4*)&mlb[((0 + qf) * 2 + 1) * 16 + g * 4];
      f32x4 m1 = *(f32x4*)&mlb[((4 + qf) * 2 + 0) * 16 + g * 4];
      f32x4 l1 = *(f32x4*)&mlb[((4 + qf) * 2 + 1) * 16 + g * 4];
      float a0[4], a1[4], rinv[4];
#pragma unroll
      for (int e = 0; e < 4; ++e) {
        float mf = fmaxf(m0[e], m1[e]);
        a0[e] = exp2f(m0[e] - mf);
        a1[e] = exp2f(m1[e] - mf);
        rinv[e] = 1.f / (l0[e] * a0[e] + l1[e] * a1[e]);
      }
#pragma unroll
      for (int df = 0; df < 4; ++df) {
        int d = df * 16 + l15;
        int ba = d * 256 + qf * 64 + g * 16;
        f32x4 o1 = *(f32x4*)((char*)smem + (ba ^ ((d & 7) << 4)));
#pragma unroll
        for (int e = 0; e < 4; ++e) {
          int qn = q0 + qf * 16 + g * 4 + e;
          float val = (o[qf][df][e] * a0[e] + o1[e] * a1[e]) * rinv[e];
          size_t off = (((size_t)n * HW) + head * 1024 + (qn >> 2)) * CCH + (qn & 3) * DH + d;
          O[off] = f2bf(val);
        }
      }
    }
  }
}

// ---------------- proj GEMM + bias + transpose to (n, c, hw) fp32 ----------------
__global__ __launch_bounds__(256) void k_proj(
    const u16* __restrict__ A, const u16* __restrict__ W,
    const float* __restrict__ bias, float* __restrict__ out) {
  __shared__ __attribute__((aligned(16))) u16 As[64 * 32];
  __shared__ __attribute__((aligned(16))) u16 Bs[64 * 32];
  int Rb = blockIdx.x * 64, Cb = blockIdx.y * 64;
  int t = threadIdx.x, lane = t & 63, wv = t >> 6;
  int wr = (wv >> 1) * 32, wc = (wv & 1) * 32;
  f32x4 acc[2][2] = {};
  for (int kb = 0; kb < CCH; kb += 32) {
    {
      int r = t >> 2, kc = t & 3;
      uint4 v = *(const uint4*)(A + ((size_t)(Rb + r)) * CCH + kb + kc * 8);
      *(uint4*)((char*)As + r * 64 + ((kc * 16) ^ ((r & 3) << 4))) = v;
    }
    {
      int k = t >> 3, jc = (t & 7) * 8;
      union { u16 u[8]; uint4 v; } tmp;
      tmp.v = *(const uint4*)(W + ((size_t)(kb + k)) * CCH + Cb + jc);
#pragma unroll
      for (int i2 = 0; i2 < 8; ++i2) {
        int j = jc + i2;
        *(u16*)((char*)Bs + j * 64 + ((k * 2) ^ ((j & 3) << 4))) = tmp.u[i2];
      }
    }
    __syncthreads();
    bf16x8 af[2], bfr[2];
#pragma unroll
    for (int f = 0; f < 2; ++f) {
      int row = wr + f * 16 + (lane & 15);
      af[f] = *(const bf16x8*)((const char*)As + row * 64 +
                               (((lane >> 4) * 16) ^ ((row & 3) << 4)));
      int col = wc + f * 16 + (lane & 15);
      bfr[f] = *(const bf16x8*)((const char*)Bs + col * 64 +
                                (((lane >> 4) * 16) ^ ((col & 3) << 4)));
    }
#pragma unroll
    for (int i2 = 0; i2 < 2; ++i2)
#pragma unroll
      for (int j2 = 0; j2 < 2; ++j2)
        acc[i2][j2] = __builtin_amdgcn_mfma_f32_16x16x32_bf16(af[i2], bfr[j2], acc[i2][j2], 0, 0, 0);
    __syncthreads();
  }
#pragma unroll
  for (int i2 = 0; i2 < 2; ++i2)
#pragma unroll
    for (int j2 = 0; j2 < 2; ++j2)
#pragma unroll
      for (int e = 0; e < 4; ++e) {
        int R = Rb + wr + i2 * 16 + (lane >> 4) * 4 + e;
        int cg = Cb + wc + j2 * 16 + (lane & 15);
        out[((size_t)((R >> 12) * CCH + cg)) * HW + (R & (HW - 1))] =
            acc[i2][j2][e] + bias[cg];
      }
}

extern "C" void kernel_launch(void* const* d_in, const int* in_sizes, int n_in,
                              void* d_out, int out_size, void* d_ws, size_t ws_size,
                              hipStream_t stream) {
  (void)in_sizes; (void)n_in; (void)out_size; (void)ws_size;
  const float* x      = (const float*)d_in[0];
  const float* gamma  = (const float*)d_in[1];
  const float* beta   = (const float*)d_in[2];
  const float* qkv_w  = (const float*)d_in[3];
  const float* proj_w = (const float*)d_in[4];
  const float* proj_b = (const float*)d_in[5];

  char* ws = (char*)d_ws;
  size_t off = 0;
  float* ab = (float*)(ws + off); off += 4096;
  u16* seq  = (u16*)(ws + off);  off += (size_t)NB * HW * CCH * 2;       // 8 MB
  u16* qwb  = (u16*)(ws + off);  off += (size_t)CCH * 3 * CCH * 2;      // 384 KB
  u16* pwb  = (u16*)(ws + off);  off += (size_t)CCH * CCH * 2;          // 128 KB
  u16* Qb   = (u16*)(ws + off);  off += (size_t)NB * HEADS * SLEN * DH * 2;  // 8 MB
  u16* Kb   = (u16*)(ws + off);  off += (size_t)NB * HEADS * SLEN * DH * 2;
  u16* Vtb  = (u16*)(ws + off);  off += (size_t)NB * HEADS * SLEN * DH * 2;
  u16* oseq = (u16*)(ws + off);  off += (size_t)NB * HW * CCH * 2;

  k_bnstats<<<256, 256, 0, stream>>>(x, gamma, beta, ab);
  k_seq<<<dim3(HW / 64, CCH / 64, NB), 256, 0, stream>>>(x, ab, seq);
  k_cvt<<<256, 256, 0, stream>>>(qkv_w, proj_w, qwb, pwb);
  k_qkv<<<dim3((NB * HW) / 64, 768 / 64), 256, 0, stream>>>(seq, qwb, Qb, Kb, Vtb);
  k_attn<<<dim3(SLEN / 64, NB * HEADS), 128, 0, stream>>>(Qb, Kb, Vtb, oseq);
  k_proj<<<dim3((NB * HW) / 64, CCH / 64), 256, 0, stream>>>(oseq, pwb, proj_b, (float*)d_out);
}

// Round 3
// 277.152 us; speedup vs baseline: 1.6194x; 1.0768x over previous
//
#include <hip/hip_runtime.h>
#include <stdint.h>

#define NB 4
#define CCH 256
#define HW 4096
#define HEADS 4
#define DH 64
#define SLEN 4096
#define EPSV 1e-5f
#define NEG_INF (-__builtin_inff())
#define QSCALE (0.125f * 1.44269504088896340736f)

typedef unsigned short u16;
typedef __bf16 bf16x8 __attribute__((ext_vector_type(8)));
typedef float f32x4 __attribute__((ext_vector_type(4)));

__device__ __forceinline__ u16 f2bf(float f) {
  union { float f; uint32_t u; } v; v.f = f;
  uint32_t r = v.u + 0x7FFFu + ((v.u >> 16) & 1u);
  return (u16)(r >> 16);
}

// ---------------- fused BN stats (blocks 0..255) + weight cvt (blocks 256..383) ----
__global__ __launch_bounds__(256) void k_pre(
    const float* __restrict__ x, const float* __restrict__ gamma,
    const float* __restrict__ beta, const float* __restrict__ qw,
    const float* __restrict__ pw, float* __restrict__ ab,
    u16* __restrict__ qwb, u16* __restrict__ pwb) {
  int t = threadIdx.x;
  if (blockIdx.x < 256) {
    int ch = blockIdx.x;
    float s = 0.f, ss = 0.f;
    for (int n = 0; n < NB; ++n) {
      const float4* p = (const float4*)(x + ((size_t)(n * CCH + ch)) * HW);
      for (int i = t; i < HW / 4; i += 256) {
        float4 v = p[i];
        s += v.x + v.y + v.z + v.w;
        ss += v.x * v.x + v.y * v.y + v.z * v.z + v.w * v.w;
      }
    }
#pragma unroll
    for (int mm = 32; mm >= 1; mm >>= 1) {
      s += __shfl_down(s, mm);
      ss += __shfl_down(ss, mm);
    }
    __shared__ float ls[4], lss[4];
    if ((t & 63) == 0) { ls[t >> 6] = s; lss[t >> 6] = ss; }
    __syncthreads();
    if (t == 0) {
      float S = 0.f, SS = 0.f;
      for (int i = 0; i < 4; ++i) { S += ls[i]; SS += lss[i]; }
      float inv = 1.0f / (float)(NB * HW);
      float mean = S * inv;
      float var = SS * inv - mean * mean;
      float a = gamma[ch] * rsqrtf(var + EPSV);
      ab[ch] = a;
      ab[CCH + ch] = beta[ch] - mean * a;
    }
  } else {
    const int NQ = CCH * 3 * CCH;  // 196608
    int i = ((blockIdx.x - 256) * 256 + t) * 8;
    const float* src = (i < NQ) ? (qw + i) : (pw + (i - NQ));
    u16* dst = (i < NQ) ? (qwb + i) : (pwb + (i - NQ));
    float4 v0 = *(const float4*)src;
    float4 v1 = *(const float4*)(src + 4);
    union { u16 u[8]; uint4 v; } o;
    o.u[0] = f2bf(v0.x); o.u[1] = f2bf(v0.y); o.u[2] = f2bf(v0.z); o.u[3] = f2bf(v0.w);
    o.u[4] = f2bf(v1.x); o.u[5] = f2bf(v1.y); o.u[6] = f2bf(v1.z); o.u[7] = f2bf(v1.w);
    *(uint4*)dst = o.v;
  }
}

// ---------------- normalize + transpose -> seq bf16 (n, hw, c) ----------------
__global__ __launch_bounds__(256) void k_seq(
    const float* __restrict__ x, const float* __restrict__ ab,
    u16* __restrict__ seq) {
  __shared__ float tile[64][65];
  int pb = blockIdx.x * 64, cb = blockIdx.y * 64, n = blockIdx.z;
  int t = threadIdx.x;
  {
    int cl = t >> 2, pc = (t & 3) * 16;
    float a = ab[cb + cl], b = ab[CCH + cb + cl];
    const float* src = x + ((size_t)(n * CCH + cb + cl)) * HW + pb + pc;
#pragma unroll
    for (int i = 0; i < 4; ++i) {
      float4 v = *(const float4*)(src + i * 4);
      tile[cl][pc + i * 4 + 0] = v.x * a + b;
      tile[cl][pc + i * 4 + 1] = v.y * a + b;
      tile[cl][pc + i * 4 + 2] = v.z * a + b;
      tile[cl][pc + i * 4 + 3] = v.w * a + b;
    }
  }
  __syncthreads();
  {
    int pl = t >> 2, cs = (t & 3) * 16;
    union { u16 u[16]; uint4 v[2]; } tmp;
#pragma unroll
    for (int i = 0; i < 16; ++i) tmp.u[i] = f2bf(tile[cs + i][pl]);
    u16* dst = seq + ((size_t)(n * HW + pb + pl)) * CCH + cb + cs;
    *(uint4*)dst = tmp.v[0];
    *(uint4*)(dst + 8) = tmp.v[1];
  }
}

// ---------------- QKV GEMM -> scatter Q(scaled)/K/Vt ----------------
__global__ __launch_bounds__(256) void k_qkv(
    const u16* __restrict__ seq, const u16* __restrict__ w,
    u16* __restrict__ Q, u16* __restrict__ K, u16* __restrict__ Vt) {
  __shared__ __attribute__((aligned(16))) u16 As[64 * 32];
  __shared__ __attribute__((aligned(16))) u16 Bs[64 * 32];
  int Rb = blockIdx.x * 64, Cb = blockIdx.y * 64;
  int t = threadIdx.x, lane = t & 63, wv = t >> 6;
  int wr = (wv >> 1) * 32, wc = (wv & 1) * 32;
  f32x4 acc[2][2] = {};
  for (int kb = 0; kb < CCH; kb += 32) {
    {
      int r = t >> 2, kc = t & 3;
      uint4 v = *(const uint4*)(seq + ((size_t)(Rb + r)) * CCH + kb + kc * 8);
      *(uint4*)((char*)As + r * 64 + ((kc * 16) ^ ((r & 3) << 4))) = v;
    }
    {
      int k = t >> 3, jc = (t & 7) * 8;
      union { u16 u[8]; uint4 v; } tmp;
      tmp.v = *(const uint4*)(w + ((size_t)(kb + k)) * 768 + Cb + jc);
#pragma unroll
      for (int i2 = 0; i2 < 8; ++i2) {
        int j = jc + i2;
        *(u16*)((char*)Bs + j * 64 + ((k * 2) ^ ((j & 3) << 4))) = tmp.u[i2];
      }
    }
    __syncthreads();
    bf16x8 af[2], bfr[2];
#pragma unroll
    for (int f = 0; f < 2; ++f) {
      int row = wr + f * 16 + (lane & 15);
      af[f] = *(const bf16x8*)((const char*)As + row * 64 +
                               (((lane >> 4) * 16) ^ ((row & 3) << 4)));
      int col = wc + f * 16 + (lane & 15);
      bfr[f] = *(const bf16x8*)((const char*)Bs + col * 64 +
                                (((lane >> 4) * 16) ^ ((col & 3) << 4)));
    }
#pragma unroll
    for (int i2 = 0; i2 < 2; ++i2)
#pragma unroll
      for (int j2 = 0; j2 < 2; ++j2)
        acc[i2][j2] = __builtin_amdgcn_mfma_f32_16x16x32_bf16(af[i2], bfr[j2], acc[i2][j2], 0, 0, 0);
    __syncthreads();
  }
#pragma unroll
  for (int i2 = 0; i2 < 2; ++i2)
#pragma unroll
    for (int j2 = 0; j2 < 2; ++j2)
#pragma unroll
      for (int e = 0; e < 4; ++e) {
        int R = Rb + wr + i2 * 16 + (lane >> 4) * 4 + e;
        int cg = Cb + wc + j2 * 16 + (lane & 15);
        int p = R & (HW - 1);
        int head = p >> 10, mq = p & 1023;
        int qn = mq * 4 + cg / 192, tt = cg % 192;
        int nhx = (R >> 12) * HEADS + head;
        float a = acc[i2][j2][e];
        if (tt < 64)
          Q[((size_t)nhx * SLEN + qn) * DH + tt] = f2bf(a * QSCALE);
        else if (tt < 128)
          K[((size_t)nhx * SLEN + qn) * DH + tt - 64] = f2bf(a);
        else
          Vt[(size_t)nhx * SLEN * DH + (size_t)(tt - 128) * SLEN + qn] = f2bf(a);
      }
}

// ---------------- flash attention: 4 waves, kv-split 4, defer-max ----------------
__global__ __launch_bounds__(256, 2) void k_attn(
    const u16* __restrict__ Q, const u16* __restrict__ K,
    const u16* __restrict__ Vt, u16* __restrict__ O) {
  __shared__ __attribute__((aligned(16))) char smem[32768 + 2048];
  float* mlA = (float*)(smem + 32768);         // [slot4][qf4][row16] m
  float* mlB = (float*)(smem + 32768 + 1024);  // [slot4][qf4][row16] l
  int q0 = blockIdx.x * 64, nh = blockIdx.y;
  int t = threadIdx.x, lane = t & 63, w = t >> 6;
  int l15 = lane & 15, g = lane >> 4;
  size_t base = (size_t)nh * SLEN * DH;
  char* Ps = smem + w * 8192;  // [64 q][64 kv] bf16, swizzled
  int swz = (l15 & 7) << 4;

  // Q fragments (B-operand: col = q = l15, k = d)
  bf16x8 qv[4][2];
#pragma unroll
  for (int qf = 0; qf < 4; ++qf) {
    const u16* qp = Q + base + (size_t)(q0 + qf * 16 + l15) * DH + g * 8;
    qv[qf][0] = *(const bf16x8*)qp;
    qv[qf][1] = *(const bf16x8*)(qp + 32);
  }

  f32x4 o[4][4] = {};
  float m[4] = {NEG_INF, NEG_INF, NEG_INF, NEG_INF};
  float lsum[4] = {0.f, 0.f, 0.f, 0.f};

  const u16* Kbase = K + base + (size_t)l15 * DH + g * 8;
  const u16* Vbase = Vt + base + (size_t)l15 * SLEN + g * 8;

  const int TILES = SLEN / 64 / 4;  // 16 per wave
  for (int tt = 0; tt < TILES; ++tt) {
    int kv0 = (w * TILES + tt) * 64;
    bf16x8 kf[4][2], vf[4][2];
#pragma unroll
    for (int cf = 0; cf < 4; ++cf) {
      const u16* kp = Kbase + (size_t)(kv0 + cf * 16) * DH;
      kf[cf][0] = *(const bf16x8*)kp;
      kf[cf][1] = *(const bf16x8*)(kp + 32);
    }
#pragma unroll
    for (int df = 0; df < 4; ++df) {
      const u16* vp = Vbase + (size_t)(df * 16) * SLEN + kv0;
      vf[df][0] = *(const bf16x8*)vp;
      vf[df][1] = *(const bf16x8*)(vp + 32);
    }
#pragma unroll
    for (int qf = 0; qf < 4; ++qf) {
      f32x4 st[4];
#pragma unroll
      for (int cf = 0; cf < 4; ++cf) {
        f32x4 a = {};
        a = __builtin_amdgcn_mfma_f32_16x16x32_bf16(kf[cf][0], qv[qf][0], a, 0, 0, 0);
        a = __builtin_amdgcn_mfma_f32_16x16x32_bf16(kf[cf][1], qv[qf][1], a, 0, 0, 0);
        st[cf] = a;
      }
      float mx = st[0][0];
#pragma unroll
      for (int cf = 0; cf < 4; ++cf)
#pragma unroll
        for (int e = 0; e < 4; ++e) mx = fmaxf(mx, st[cf][e]);
      mx = fmaxf(mx, __shfl_xor(mx, 16));
      mx = fmaxf(mx, __shfl_xor(mx, 32));
      // defer-max: only rescale when the tile max grew materially
      if (!__all(mx <= m[qf] + 8.0f)) {
        float mn = fmaxf(m[qf], mx);
        float al = exp2f(m[qf] - mn);
        m[qf] = mn;
        lsum[qf] *= al;
#pragma unroll
        for (int e = 0; e < 4; ++e) {
          float ae = __shfl(al, (lane & 48) | (((lane >> 4) << 2) + e));
#pragma unroll
          for (int df = 0; df < 4; ++df) o[qf][df][e] *= ae;
        }
      }
      float ls = 0.f;
#pragma unroll
      for (int cf = 0; cf < 4; ++cf) {
        union { __bf16 h[4]; uint2 v; } pk;
#pragma unroll
        for (int e = 0; e < 4; ++e) {
          float p = exp2f(st[cf][e] - m[qf]);
          ls += p;
          pk.h[e] = (__bf16)p;
        }
        *(uint2*)(Ps + (qf * 16 + l15) * 128 + ((cf * 32 + g * 8) ^ swz)) = pk.v;
      }
      lsum[qf] += ls;
    }
#pragma unroll
    for (int qf = 0; qf < 4; ++qf) {
#pragma unroll
      for (int ks = 0; ks < 2; ++ks) {
        bf16x8 pa = *(const bf16x8*)(Ps + (qf * 16 + l15) * 128 + ((ks * 64 + g * 16) ^ swz));
#pragma unroll
        for (int df = 0; df < 4; ++df)
          o[qf][df] = __builtin_amdgcn_mfma_f32_16x16x32_bf16(pa, vf[df][ks], o[qf][df], 0, 0, 0);
      }
    }
  }
  // finalize per-wave state: reduce l across g, convert m/l to C-frag layout
#pragma unroll
  for (int qf = 0; qf < 4; ++qf) {
    lsum[qf] += __shfl_xor(lsum[qf], 16);
    lsum[qf] += __shfl_xor(lsum[qf], 32);
  }
  f32x4 me[4], le[4];
#pragma unroll
  for (int qf = 0; qf < 4; ++qf)
#pragma unroll
    for (int e = 0; e < 4; ++e) {
      int idx = (lane & 48) | (((lane >> 4) & 3) << 2) | e;
      me[qf][e] = __shfl(m[qf], idx);
      le[qf][e] = __shfl(lsum[qf], idx);
    }

  auto publish = [&](char* reg, int s) {
#pragma unroll
    for (int qf = 0; qf < 4; ++qf) {
#pragma unroll
      for (int df = 0; df < 4; ++df) {
        int d = df * 16 + l15;
        *(f32x4*)(reg + ((d * 256 + qf * 64 + g * 16) ^ ((d & 7) << 4))) = o[qf][df];
      }
      if (l15 == 0) {
        *(f32x4*)&mlA[(s * 4 + qf) * 16 + g * 4] = me[qf];
        *(f32x4*)&mlB[(s * 4 + qf) * 16 + g * 4] = le[qf];
      }
    }
  };
  auto merge = [&](char* reg, int s) {
#pragma unroll
    for (int qf = 0; qf < 4; ++qf) {
      f32x4 mp = *(f32x4*)&mlA[(s * 4 + qf) * 16 + g * 4];
      f32x4 lp = *(f32x4*)&mlB[(s * 4 + qf) * 16 + g * 4];
      f32x4 op[4];
#pragma unroll
      for (int df = 0; df < 4; ++df) {
        int d = df * 16 + l15;
        op[df] = *(f32x4*)(reg + ((d * 256 + qf * 64 + g * 16) ^ ((d & 7) << 4)));
      }
#pragma unroll
      for (int e = 0; e < 4; ++e) {
        float mf = fmaxf(me[qf][e], mp[e]);
        float as = exp2f(me[qf][e] - mf), ap = exp2f(mp[e] - mf);
        le[qf][e] = le[qf][e] * as + lp[e] * ap;
        me[qf][e] = mf;
#pragma unroll
        for (int df = 0; df < 4; ++df)
          o[qf][df][e] = o[qf][df][e] * as + op[df][e] * ap;
      }
    }
  };

  __syncthreads();  // done with Ps
  if (w == 1) publish(smem, 1);
  if (w == 3) publish(smem + 16384, 3);
  __syncthreads();
  if (w == 0) merge(smem, 1);
  if (w == 2) merge(smem + 16384, 3);
  __syncthreads();
  if (w == 2) publish(smem, 2);
  __syncthreads();
  if (w == 0) {
    merge(smem, 2);
    int n = nh >> 2, head = nh & 3;
#pragma unroll
    for (int qf = 0; qf < 4; ++qf) {
      f32x4 rinv;
#pragma unroll
      for (int e = 0; e < 4; ++e) rinv[e] = 1.f / le[qf][e];
#pragma unroll
      for (int df = 0; df < 4; ++df) {
        int d = df * 16 + l15;
#pragma unroll
        for (int e = 0; e < 4; ++e) {
          int qn = q0 + qf * 16 + g * 4 + e;
          size_t off = (((size_t)n * HW) + head * 1024 + (qn >> 2)) * CCH + (qn & 3) * DH + d;
          O[off] = f2bf(o[qf][df][e] * rinv[e]);
        }
      }
    }
  }
}

// ---------------- proj GEMM + bias + transpose to (n, c, hw) fp32 ----------------
__global__ __launch_bounds__(256) void k_proj(
    const u16* __restrict__ A, const u16* __restrict__ W,
    const float* __restrict__ bias, float* __restrict__ out) {
  __shared__ __attribute__((aligned(16))) u16 As[64 * 32];
  __shared__ __attribute__((aligned(16))) u16 Bs[64 * 32];
  int Rb = blockIdx.x * 64, Cb = blockIdx.y * 64;
  int t = threadIdx.x, lane = t & 63, wv = t >> 6;
  int wr = (wv >> 1) * 32, wc = (wv & 1) * 32;
  f32x4 acc[2][2] = {};
  for (int kb = 0; kb < CCH; kb += 32) {
    {
      int r = t >> 2, kc = t & 3;
      uint4 v = *(const uint4*)(A + ((size_t)(Rb + r)) * CCH + kb + kc * 8);
      *(uint4*)((char*)As + r * 64 + ((kc * 16) ^ ((r & 3) << 4))) = v;
    }
    {
      int k = t >> 3, jc = (t & 7) * 8;
      union { u16 u[8]; uint4 v; } tmp;
      tmp.v = *(const uint4*)(W + ((size_t)(kb + k)) * CCH + Cb + jc);
#pragma unroll
      for (int i2 = 0; i2 < 8; ++i2) {
        int j = jc + i2;
        *(u16*)((char*)Bs + j * 64 + ((k * 2) ^ ((j & 3) << 4))) = tmp.u[i2];
      }
    }
    __syncthreads();
    bf16x8 af[2], bfr[2];
#pragma unroll
    for (int f = 0; f < 2; ++f) {
      int row = wr + f * 16 + (lane & 15);
      af[f] = *(const bf16x8*)((const char*)As + row * 64 +
                               (((lane >> 4) * 16) ^ ((row & 3) << 4)));
      int col = wc + f * 16 + (lane & 15);
      bfr[f] = *(const bf16x8*)((const char*)Bs + col * 64 +
                                (((lane >> 4) * 16) ^ ((col & 3) << 4)));
    }
#pragma unroll
    for (int i2 = 0; i2 < 2; ++i2)
#pragma unroll
      for (int j2 = 0; j2 < 2; ++j2)
        acc[i2][j2] = __builtin_amdgcn_mfma_f32_16x16x32_bf16(af[i2], bfr[j2], acc[i2][j2], 0, 0, 0);
    __syncthreads();
  }
#pragma unroll
  for (int i2 = 0; i2 < 2; ++i2)
#pragma unroll
    for (int j2 = 0; j2 < 2; ++j2)
#pragma unroll
      for (int e = 0; e < 4; ++e) {
        int R = Rb + wr + i2 * 16 + (lane >> 4) * 4 + e;
        int cg = Cb + wc + j2 * 16 + (lane & 15);
        out[((size_t)((R >> 12) * CCH + cg)) * HW + (R & (HW - 1))] =
            acc[i2][j2][e] + bias[cg];
      }
}

extern "C" void kernel_launch(void* const* d_in, const int* in_sizes, int n_in,
                              void* d_out, int out_size, void* d_ws, size_t ws_size,
                              hipStream_t stream) {
  (void)in_sizes; (void)n_in; (void)out_size; (void)ws_size;
  const float* x      = (const float*)d_in[0];
  const float* gamma  = (const float*)d_in[1];
  const float* beta   = (const float*)d_in[2];
  const float* qkv_w  = (const float*)d_in[3];
  const float* proj_w = (const float*)d_in[4];
  const float* proj_b = (const float*)d_in[5];

  char* ws = (char*)d_ws;
  size_t off = 0;
  float* ab = (float*)(ws + off); off += 4096;
  u16* seq  = (u16*)(ws + off);  off += (size_t)NB * HW * CCH * 2;       // 8 MB
  u16* qwb  = (u16*)(ws + off);  off += (size_t)CCH * 3 * CCH * 2;      // 384 KB
  u16* pwb  = (u16*)(ws + off);  off += (size_t)CCH * CCH * 2;          // 128 KB
  u16* Qb   = (u16*)(ws + off);  off += (size_t)NB * HEADS * SLEN * DH * 2;  // 8 MB
  u16* Kb   = (u16*)(ws + off);  off += (size_t)NB * HEADS * SLEN * DH * 2;
  u16* Vtb  = (u16*)(ws + off);  off += (size_t)NB * HEADS * SLEN * DH * 2;
  u16* oseq = (u16*)(ws + off);  off += (size_t)NB * HW * CCH * 2;

  k_pre<<<384, 256, 0, stream>>>(x, gamma, beta, qkv_w, proj_w, ab, qwb, pwb);
  k_seq<<<dim3(HW / 64, CCH / 64, NB), 256, 0, stream>>>(x, ab, seq);
  k_qkv<<<dim3((NB * HW) / 64, 768 / 64), 256, 0, stream>>>(seq, qwb, Qb, Kb, Vtb);
  k_attn<<<dim3(SLEN / 64, NB * HEADS), 256, 0, stream>>>(Qb, Kb, Vtb, oseq);
  k_proj<<<dim3((NB * HW) / 64, CCH / 64), 256, 0, stream>>>(oseq, pwb, proj_b, (float*)d_out);
}